// Round 4
// baseline (15.230 us; speedup 1.0000x reference)
//
#include <hip/hip_runtime.h>

// DNF network: B=256, I=512, O=128, K=8, H=O*K=1024
// out[b,o] = 1 - prod_k(1 - Wo[o,k] * prod_i(Wa[i,o*K+k]*x[b,i] + 1 - Wa[i,o*K+k]))
// gate = 1 + Wa*(x-1)  ->  stage xm1 = x-1 in LDS, inner op = pk_fma(wa2, x2, 1).
//
// Single fused kernel. lane = h within 64-wide h-tile (Wa coalesced 256B/wave);
// 8 waves = 8 i-segments; 8 batch rows per block held as 4 float2 accumulators
// processed with packed-FP32 VOP3P ops (v_pk_fma_f32 / v_pk_mul_f32): 2 gates
// per lane per instruction -> inner loop 10 VALU instr/iter instead of 17.

#define B_ 256
#define I_ 512
#define O_ 128
#define K_ 8
#define H_ 1024
#define NB 8          // batch rows per block (4 float2 pairs)
#define SW 8          // i-segment waves per block

typedef float v2f __attribute__((ext_vector_type(2)));

__device__ __forceinline__ v2f pk_fma(v2f a, v2f b, v2f c) {
    v2f d;
    asm("v_pk_fma_f32 %0, %1, %2, %3" : "=v"(d) : "v"(a), "v"(b), "v"(c));
    return d;
}
__device__ __forceinline__ v2f pk_mul(v2f a, v2f b) {
    v2f d;
    asm("v_pk_mul_f32 %0, %1, %2" : "=v"(d) : "v"(a), "v"(b));
    return d;
}

__global__ __launch_bounds__(512) void dnf_fused(const float* __restrict__ x,
                                                 const float* __restrict__ Wa,
                                                 const float* __restrict__ Wo,
                                                 float* __restrict__ out) {
    __shared__ v2f xm1[I_][NB / 2];          // 16 KB, [i][b-pair]
    __shared__ v2f red[SW - 1][64][NB / 2];  // 14 KB

    const int tid  = threadIdx.x;
    const int lane = tid & 63;
    const int w    = tid >> 6;               // 0..7 = i-segment
    const int ht   = blockIdx.x;             // 0..15 h-tile
    const int bg   = blockIdx.y;             // 0..31 b-group
    const int h    = ht * 64 + lane;
    const int b0   = bg * NB;

    // Stage xm1[i][:] = x[b0..b0+7][i] - 1. Thread t owns row i = t.
    {
        const float* xp = x + (size_t)b0 * I_ + tid;
        float v[NB];
#pragma unroll
        for (int b = 0; b < NB; ++b) v[b] = xp[(size_t)b * I_] - 1.0f;
#pragma unroll
        for (int p = 0; p < NB / 2; ++p) {
            v2f t = {v[2 * p], v[2 * p + 1]};
            xm1[tid][p] = t;
        }
    }
    __syncthreads();

    const v2f one2 = {1.0f, 1.0f};
    v2f acc[NB / 2];
#pragma unroll
    for (int p = 0; p < NB / 2; ++p) acc[p] = one2;

    const int i0 = w * (I_ / SW);
    const float* __restrict__ wp = Wa + (size_t)i0 * H_ + h;

#pragma unroll 4
    for (int s = 0; s < I_ / SW; ++s) {
        float wac = __builtin_amdgcn_fmed3f(wp[(size_t)s * H_], 0.0f, 1.0f);
        v2f wa2 = {wac, wac};
        const v2f* xr = &xm1[i0 + s][0];
        v2f u0 = xr[0], u1 = xr[1], u2 = xr[2], u3 = xr[3];
        acc[0] = pk_mul(acc[0], pk_fma(wa2, u0, one2));
        acc[1] = pk_mul(acc[1], pk_fma(wa2, u1, one2));
        acc[2] = pk_mul(acc[2], pk_fma(wa2, u2, one2));
        acc[3] = pk_mul(acc[3], pk_fma(wa2, u3, one2));
    }

    // Combine the 8 i-segment partial products per (h, b).
    if (w > 0) {
#pragma unroll
        for (int p = 0; p < NB / 2; ++p) red[w - 1][lane][p] = acc[p];
    }
    __syncthreads();

    if (w == 0) {
#pragma unroll
        for (int ww = 0; ww < SW - 1; ++ww) {
#pragma unroll
            for (int p = 0; p < NB / 2; ++p)
                acc[p] = pk_mul(acc[p], red[ww][lane][p]);
        }

        // Fuzzy OR over k: lane = o_local*8 + k, reduce within 8-lane groups.
        const float wo = __builtin_amdgcn_fmed3f(Wo[h], 0.0f, 1.0f);
        const int og = ht * 8 + (lane >> 3);
        float outv[NB];
#pragma unroll
        for (int p = 0; p < NB / 2; ++p) {
#pragma unroll
            for (int e = 0; e < 2; ++e) {
                float t = fmaf(-wo, acc[p][e], 1.0f);   // 1 - wo*and
                t *= __shfl_xor(t, 1);
                t *= __shfl_xor(t, 2);
                t *= __shfl_xor(t, 4);
                outv[2 * p + e] = 1.0f - t;
            }
        }
        if ((lane & 7) == 0) {
#pragma unroll
            for (int b = 0; b < NB; ++b)
                out[(size_t)(b0 + b) * O_ + og] = outv[b];
        }
    }
}

extern "C" void kernel_launch(void* const* d_in, const int* in_sizes, int n_in,
                              void* d_out, int out_size, void* d_ws, size_t ws_size,
                              hipStream_t stream) {
    const float* x  = (const float*)d_in[0];   // (B, I, 1)
    const float* Wa = (const float*)d_in[1];   // (I, H)
    const float* Wo = (const float*)d_in[2];   // (H, 1)
    float* out = (float*)d_out;                // (B, O)
    (void)d_ws; (void)ws_size; (void)in_sizes; (void)n_in; (void)out_size;

    dnf_fused<<<dim3(H_ / 64, B_ / NB), 512, 0, stream>>>(x, Wa, Wo, out);
}

// Round 5
// 14.298 us; speedup vs baseline: 1.0651x; 1.0651x over previous
//
#include <hip/hip_runtime.h>

// DNF network: B=256, I=512, O=128, K=8, H=O*K=1024
// out[b,o] = 1 - prod_k(1 - Wo[o,k] * prod_i(Wa[i,o*K+k]*x[b,i] + 1 - Wa[i,o*K+k]))
// gate = 1 + Wa*(x-1)  ->  stage xm1 = x-1 in LDS, inner op = fmaf(wa, xm1, 1).
//
// Single fused kernel (no workspace, 1 graph node):
//   lane  = h within a 64-wide h-tile (h = o*8+k)  -> Wa loads coalesced 256B/wave
//   block = (h-tile, b-group of 8) ; 8 waves = 8 i-segments of 64
//   xm1 for the block's 8 batch rows staged once in LDS (16 KB), read as
//   uniform-address ds_read_b128 broadcasts (conflict-free).
//   i-segment partial products combined via LDS; fuzzy-OR over k via
//   __shfl_xor within 8-lane groups.
//
// R4 lesson: inline-asm v_pk_fma_f32/v_pk_mul_f32 versions REGRESSED
// (14.3 -> 15.2 us): asm defeats compiler scheduling across the unroll
// window and adds movs for pair-aligned operands. Scalar + compiler
// scheduling is faster. Kernel is ~2.5-3 us; remaining total is
// ~12 us/node graph-replay overhead (fit across R1/R2/R3).

#define B_ 256
#define I_ 512
#define O_ 128
#define K_ 8
#define H_ 1024
#define NB 8          // batch rows per block
#define SW 8          // i-segment waves per block

__global__ __launch_bounds__(512) void dnf_fused(const float* __restrict__ x,
                                                 const float* __restrict__ Wa,
                                                 const float* __restrict__ Wo,
                                                 float* __restrict__ out) {
    __shared__ float xm1[I_][NB];            // 16 KB, [i][b]
    __shared__ float red[SW - 1][64][NB];    // 14 KB

    const int tid  = threadIdx.x;
    const int lane = tid & 63;
    const int w    = tid >> 6;               // 0..7 = i-segment
    const int ht   = blockIdx.x;             // 0..15 h-tile
    const int bg   = blockIdx.y;             // 0..31 b-group
    const int h    = ht * 64 + lane;
    const int b0   = bg * NB;

    // Stage xm1[i][b] = x[b0+b][i] - 1. Thread t owns row i = t.
    // Per wave, fixed b: 64 consecutive floats -> coalesced.
    {
        const float* xp = x + (size_t)b0 * I_ + tid;
        float v[NB];
#pragma unroll
        for (int b = 0; b < NB; ++b) v[b] = xp[(size_t)b * I_] - 1.0f;
#pragma unroll
        for (int b = 0; b < NB; ++b) xm1[tid][b] = v[b];
    }
    __syncthreads();

    float acc[NB];
#pragma unroll
    for (int b = 0; b < NB; ++b) acc[b] = 1.0f;

    const int i0 = w * (I_ / SW);
    const float* __restrict__ wp = Wa + (size_t)i0 * H_ + h;

#pragma unroll 4
    for (int s = 0; s < I_ / SW; ++s) {
        float wa = __builtin_amdgcn_fmed3f(wp[(size_t)s * H_], 0.0f, 1.0f);
        const float4* xr = (const float4*)&xm1[i0 + s][0];
        float4 u0 = xr[0];
        float4 u1 = xr[1];
        acc[0] *= fmaf(wa, u0.x, 1.0f);
        acc[1] *= fmaf(wa, u0.y, 1.0f);
        acc[2] *= fmaf(wa, u0.z, 1.0f);
        acc[3] *= fmaf(wa, u0.w, 1.0f);
        acc[4] *= fmaf(wa, u1.x, 1.0f);
        acc[5] *= fmaf(wa, u1.y, 1.0f);
        acc[6] *= fmaf(wa, u1.z, 1.0f);
        acc[7] *= fmaf(wa, u1.w, 1.0f);
    }

    // Combine the 8 i-segment partial products per (h, b).
    if (w > 0) {
        float4* r = (float4*)&red[w - 1][lane][0];
        r[0] = make_float4(acc[0], acc[1], acc[2], acc[3]);
        r[1] = make_float4(acc[4], acc[5], acc[6], acc[7]);
    }
    __syncthreads();

    if (w == 0) {
#pragma unroll
        for (int ww = 0; ww < SW - 1; ++ww) {
            const float4* r = (const float4*)&red[ww][lane][0];
            float4 p0 = r[0];
            float4 p1 = r[1];
            acc[0] *= p0.x; acc[1] *= p0.y; acc[2] *= p0.z; acc[3] *= p0.w;
            acc[4] *= p1.x; acc[5] *= p1.y; acc[6] *= p1.z; acc[7] *= p1.w;
        }

        // Fuzzy OR over k: lane = o_local*8 + k, reduce within 8-lane groups.
        const float wo = __builtin_amdgcn_fmed3f(Wo[h], 0.0f, 1.0f);
        const int og = ht * 8 + (lane >> 3);
        float outv[NB];
#pragma unroll
        for (int b = 0; b < NB; ++b) {
            float t = fmaf(-wo, acc[b], 1.0f);   // 1 - wo*and
            t *= __shfl_xor(t, 1);
            t *= __shfl_xor(t, 2);
            t *= __shfl_xor(t, 4);
            outv[b] = 1.0f - t;
        }
        if ((lane & 7) == 0) {
#pragma unroll
            for (int b = 0; b < NB; ++b)
                out[(size_t)(b0 + b) * O_ + og] = outv[b];
        }
    }
}

extern "C" void kernel_launch(void* const* d_in, const int* in_sizes, int n_in,
                              void* d_out, int out_size, void* d_ws, size_t ws_size,
                              hipStream_t stream) {
    const float* x  = (const float*)d_in[0];   // (B, I, 1)
    const float* Wa = (const float*)d_in[1];   // (I, H)
    const float* Wo = (const float*)d_in[2];   // (H, 1)
    float* out = (float*)d_out;                // (B, O)
    (void)d_ws; (void)ws_size; (void)in_sizes; (void)n_in; (void)out_size;

    dnf_fused<<<dim3(H_ / 64, B_ / NB), 512, 0, stream>>>(x, Wa, Wo, out);
}